// Round 15
// baseline (27.218 us; speedup 1.0000x reference)
//
#include <hip/hip_runtime.h>
#include <hip/hip_bf16.h>

#define TOKENS 32
#define KDIM   4096
#define NDIM   11008
#define GSZ    64
#define KP     (KDIM/2)          // qweight row length in int32 (2048)
#define NGRP   (KDIM/GSZ)        // 64 groups
#define OUTK   8                 // K-splits across blocks
#define BLK_COLS 128             // 4 colWaves * 32 cols
#define NBLK_C (NDIM/BLK_COLS)   // 86
#define NBC_PAD 88               // padded col-groups for co-location remap
#define KSLICE (KDIM/OUTK)       // 512 k per block
#define GPW    (KSLICE/2/GSZ)    // 4 groups per wave (2 inner ksegs)
#define PART_ELEMS (TOKENS*NDIM) // 352256

typedef float  f32x4 __attribute__((ext_vector_type(4)));
typedef int    i32x4 __attribute__((ext_vector_type(4)));
typedef short  s16x8 __attribute__((ext_vector_type(8)));
typedef _Float16 f16x2 __attribute__((ext_vector_type(2)));
typedef _Float16 f16x8 __attribute__((ext_vector_type(8)));

// Main GEMM (r13 inner structure, 20.2us base) + FENCE-FREE fused epilogue.
// Remap: ob=(bi>>3)&7, bc=(bi&7)+8*(bi>>6), grid 704 (88 bc x 8 ob; bc>=86
// exits). XCD = bi%8 = bc&7 -> all 8 K-split blocks of a column group land on
// ONE XCD (round-robin dispatch). Partial stores are write-through to that
// XCD's shared L2; __syncthreads drains vmcnt; then a plain RELAXED atomicAdd
// (L2 op, no fence emitted -- r11's __threadfence caused a 300us L2-writeback
// storm) counts arrivals. 8th block sums partials via sc0 loads (L1-bypass,
// __hip_atomic_load relaxed/agent), fixed o-order -> deterministic, + bias.
// Even if dispatch != round-robin, partial values are replay-invariant, so
// output still converges correct (risk is timing, not correctness).
// DEQUANT (f16 packed, exact -1024 subtract; r5: no large-const FMA folding).
__global__ __launch_bounds__(512, 2) void awq_gemm2(
    const int* __restrict__ qw, const float* __restrict__ sc,
    const float* __restrict__ zp, const float* __restrict__ xf,
    float* __restrict__ partial, int* __restrict__ cnt,
    const float* __restrict__ bias, float* __restrict__ out) {
    __shared__ unsigned short xs[TOKENS * KSLICE];   // 32 KB (reused for reduce)
    __shared__ int lastFlag;

    const int tid  = threadIdx.x;
    const int lane = tid & 63;
    const int wid  = tid >> 6;       // 0..7
    const int cw   = wid & 3;        // colWave
    const int ks   = wid >> 2;       // inner kseg 0..1
    const int ob   = (blockIdx.x >> 3) & 7;          // outer kseg
    const int bc   = (blockIdx.x & 7) + 8 * (blockIdx.x >> 6);  // col group
    if (bc >= NBLK_C) return;                        // padding blocks
    const int K0   = ob * KSLICE;

    const int col  = lane & 15;
    const int kg   = lane >> 4;                      // k-subgroup 0..3
    const int n0   = bc * BLK_COLS + cw * 32 + col;  // colset-0 column
    const int sh0  = 8 * (n0 & 3);
    const int* qp0 = qw + (n0 >> 2) * KP + kg * 4;   // colset-1 = +4*KP ints

    struct GD { float s0, z0, s1, z1; i32x4 qa0, qa1, qb0, qb1; };

    auto LOADG = [&](GD& d, int gl) {
        gl = gl < GPW ? gl : GPW - 1;                // clamp prefetch overhang
        const int gg = ob * (NGRP / OUTK) + ks * GPW + gl;  // global group
        d.s0 = sc[gg * NDIM + n0];        d.z0 = zp[gg * NDIM + n0];
        d.s1 = sc[gg * NDIM + n0 + 16];   d.z1 = zp[gg * NDIM + n0 + 16];
        const int* q = qp0 + gg * 32;
        d.qa0 = *reinterpret_cast<const i32x4*>(q);
        d.qa1 = *reinterpret_cast<const i32x4*>(q + 16);
        d.qb0 = *reinterpret_cast<const i32x4*>(q + 4 * KP);
        d.qb1 = *reinterpret_cast<const i32x4*>(q + 4 * KP + 16);
    };

    // ---- q-prefetch for groups 0/1 issued BEFORE staging ----
    GD gA, gB;
    LOADG(gA, 0);
    LOADG(gB, 1);

    // ---- stage x slice: f32 global -> f16 swizzled LDS (32KB) ----
#pragma unroll
    for (int it = 0; it < 4; ++it) {
        const int lin  = it * 8192 + tid * 16;       // byte offset in f16 slice
        const int tok  = lin >> 10;
        const int kloc = (lin & 1023) >> 1;
        const float* xp = xf + tok * KDIM + K0 + kloc;
        f32x4 u0 = *reinterpret_cast<const f32x4*>(xp);
        f32x4 u1 = *reinterpret_cast<const f32x4*>(xp + 4);
        s16x8 v;
#pragma unroll
        for (int e = 0; e < 4; ++e) {
            v[e]     = __builtin_bit_cast(short, (_Float16)u0[e]);
            v[e + 4] = __builtin_bit_cast(short, (_Float16)u1[e]);
        }
        *reinterpret_cast<s16x8*>(
            reinterpret_cast<char*>(xs) + (lin ^ ((tok & 7) << 4))) = v;
    }
    __syncthreads();

    f32x4 acc00 = {0,0,0,0}, acc01 = {0,0,0,0};      // [colset][Mtile]
    f32x4 acc10 = {0,0,0,0}, acc11 = {0,0,0,0};

    auto LDSA = [&](int tok, int c) -> f16x8 {       // a-frag from swizzled LDS
        const int inrow = ((c << 6) + (kg << 4)) ^ ((tok & 7) << 4);
        return *reinterpret_cast<const f16x8*>(
            reinterpret_cast<const char*>(xs) + (tok << 10) + inrow);
    };

    const f16x2 m1024 = {(_Float16)(-1024.0f), (_Float16)(-1024.0f)};

    auto DQ = [&](const i32x4& q, f16x2 s2, f16x2 c2) -> f16x8 {
        i32x4 wu;
#pragma unroll
        for (int dd = 0; dd < 4; ++dd) {
            const int t = q[dd] >> sh0;
            const unsigned u = (unsigned)((t & 15) | ((t & 0xF0) << 12)) | 0x64006400u;
            f16x2 qv = __builtin_bit_cast(f16x2, u);
            f16x2 q2 = qv + m1024;                   // exact: q as f16 pair
            f16x2 w  = __builtin_elementwise_fma(q2, s2, c2);
            wu[dd] = __builtin_bit_cast(int, w);
        }
        return __builtin_bit_cast(f16x8, wu);
    };

    auto COMPUTE = [&](const GD& d, int gl) {
        const int c0 = ks * 8 + gl * 2;              // local K32-chunk
        f16x8 a00 = LDSA(col, c0),      a01 = LDSA(col + 16, c0);
        f16x8 a10 = LDSA(col, c0 + 1),  a11 = LDSA(col + 16, c0 + 1);
        const _Float16 hs0 = (_Float16)d.s0, hs1 = (_Float16)d.s1;
        const _Float16 hc0 = (_Float16)(-d.z0 * d.s0);
        const _Float16 hc1 = (_Float16)(-d.z1 * d.s1);
        const f16x2 s20 = {hs0, hs0}, c20 = {hc0, hc0};
        const f16x2 s21 = {hs1, hs1}, c21 = {hc1, hc1};
        f16x8 w00 = DQ(d.qa0, s20, c20), w01 = DQ(d.qa1, s20, c20);
        f16x8 w10 = DQ(d.qb0, s21, c21), w11 = DQ(d.qb1, s21, c21);
        acc00 = __builtin_amdgcn_mfma_f32_16x16x32_f16(a00, w00, acc00, 0, 0, 0);
        acc01 = __builtin_amdgcn_mfma_f32_16x16x32_f16(a01, w00, acc01, 0, 0, 0);
        acc10 = __builtin_amdgcn_mfma_f32_16x16x32_f16(a00, w10, acc10, 0, 0, 0);
        acc11 = __builtin_amdgcn_mfma_f32_16x16x32_f16(a01, w10, acc11, 0, 0, 0);
        acc00 = __builtin_amdgcn_mfma_f32_16x16x32_f16(a10, w01, acc00, 0, 0, 0);
        acc01 = __builtin_amdgcn_mfma_f32_16x16x32_f16(a11, w01, acc01, 0, 0, 0);
        acc10 = __builtin_amdgcn_mfma_f32_16x16x32_f16(a10, w11, acc10, 0, 0, 0);
        acc11 = __builtin_amdgcn_mfma_f32_16x16x32_f16(a11, w11, acc11, 0, 0, 0);
    };

#pragma unroll
    for (int gl = 0; gl < GPW; gl += 2) {
        COMPUTE(gA, gl);     LOADG(gA, gl + 2);
        COMPUTE(gB, gl + 1); LOADG(gB, gl + 3);
    }

    // ---- inner-kseg reduction through LDS (reuse xs) ----
    __syncthreads();
    float (*red)[64][17] = reinterpret_cast<float (*)[64][17]>(xs);
    if (ks == 1) {
#pragma unroll
        for (int e = 0; e < 4; ++e) {
            red[cw][lane][e]      = acc00[e];
            red[cw][lane][4 + e]  = acc01[e];
            red[cw][lane][8 + e]  = acc10[e];
            red[cw][lane][12 + e] = acc11[e];
        }
    }
    __syncthreads();
    if (ks == 0) {
#pragma unroll
        for (int e = 0; e < 4; ++e) {
            acc00[e] += red[cw][lane][e];
            acc01[e] += red[cw][lane][4 + e];
            acc10[e] += red[cw][lane][8 + e];
            acc11[e] += red[cw][lane][12 + e];
        }
        // D layout (verified m89/m91): col = lane&15, row = (lane>>4)*4 + r
        float* pb = partial + (size_t)ob * PART_ELEMS;
#pragma unroll
        for (int r = 0; r < 4; ++r) {
            const int t = kg * 4 + r;
            pb[t * NDIM + n0]             = acc00[r];
            pb[(t + 16) * NDIM + n0]      = acc01[r];
            pb[t * NDIM + n0 + 16]        = acc10[r];
            pb[(t + 16) * NDIM + n0 + 16] = acc11[r];
        }
    }

    // ---- fence-free fused epilogue (same-XCD L2 visibility) ----
    __syncthreads();                         // drains vmcnt: partials are in L2
    if (tid == 0)
        lastFlag = (atomicAdd(&cnt[bc], 1) == OUTK - 1);   // relaxed, no fence
    __syncthreads();
    if (lastFlag) {
        const int c  = bc * BLK_COLS + (tid & 127);
        const int rb = (tid >> 7) * 8;       // rows rb..rb+7
        const float bv = bias[c];
#pragma unroll
        for (int r = 0; r < 8; ++r) {
            const int row = rb + r;
            float sum = 0.f;
#pragma unroll
            for (int o = 0; o < OUTK; ++o)   // fixed order -> deterministic
                sum += __hip_atomic_load(
                    &partial[(size_t)o * PART_ELEMS + row * NDIM + c],
                    __ATOMIC_RELAXED, __HIP_MEMORY_SCOPE_AGENT);  // sc0: skip L1
            out[row * NDIM + c] = sum + bv;
        }
    }
}

// Fallback (ws too small): round-7 kernel, bf16 path, no ws usage.
__global__ __launch_bounds__(256, 3) void awq_gemm_fb(
    const int* __restrict__ qw, const float* __restrict__ sc,
    const float* __restrict__ zp, const float* __restrict__ bias,
    const float* __restrict__ xf, float* __restrict__ out) {
    const int lane = threadIdx.x & 63;
    const int kseg = threadIdx.x >> 6;
    const int col  = lane & 15;
    const int kg   = lane >> 4;
    const int n    = blockIdx.x * 16 + col;
    const int sh0  = 8 * (n & 3);
    const int* qp  = qw + (n >> 2) * KP + kg * 4;
    const int r0 = col, r1 = col + 16;

    f32x4 acc0 = {0,0,0,0}, acc1 = {0,0,0,0};

    auto cvt8 = [](const float* p) {
        f32x4 u0 = *reinterpret_cast<const f32x4*>(p);
        f32x4 u1 = *reinterpret_cast<const f32x4*>(p + 4);
        s16x8 o;
#pragma unroll
        for (int e = 0; e < 4; ++e) {
            o[e]     = __builtin_bit_cast(short, __float2bfloat16(u0[e]));
            o[e + 4] = __builtin_bit_cast(short, __float2bfloat16(u1[e]));
        }
        return o;
    };

    const int g_lo = kseg * (NGRP / 4), g_hi = g_lo + (NGRP / 4);
#pragma unroll 2
    for (int g = g_lo; g < g_hi; ++g) {
        const float s = sc[g * NDIM + n];
        const float bz = -zp[g * NDIM + n] * s;
#pragma unroll
        for (int h = 0; h < 2; ++h) {
            const int chunk = 2 * g + h;
            i32x4 q = *reinterpret_cast<const i32x4*>(qp + chunk * 16);
            const float* p0 = xf + r0 * KDIM + chunk * 32 + kg * 8;
            const float* p1 = xf + r1 * KDIM + chunk * 32 + kg * 8;
            s16x8 a0 = cvt8(p0), a1 = cvt8(p1);
            s16x8 wf;
#pragma unroll
            for (int dd = 0; dd < 4; ++dd) {
                const int qd = q[dd];
                float w0 = (float)((qd >> sh0) & 15) * s + bz;
                float w1 = (float)((qd >> (sh0 + 4)) & 15) * s + bz;
                wf[2 * dd]     = __builtin_bit_cast(short, __float2bfloat16(w0));
                wf[2 * dd + 1] = __builtin_bit_cast(short, __float2bfloat16(w1));
            }
            acc0 = __builtin_amdgcn_mfma_f32_16x16x32_bf16(a0, wf, acc0, 0, 0, 0);
            acc1 = __builtin_amdgcn_mfma_f32_16x16x32_bf16(a1, wf, acc1, 0, 0, 0);
        }
    }

    __shared__ float red[3][64][9];
    if (kseg != 0) {
#pragma unroll
        for (int e = 0; e < 4; ++e) {
            red[kseg - 1][lane][e]     = acc0[e];
            red[kseg - 1][lane][4 + e] = acc1[e];
        }
    }
    __syncthreads();
    if (kseg == 0) {
#pragma unroll
        for (int ss = 0; ss < 3; ++ss)
#pragma unroll
            for (int e = 0; e < 4; ++e) {
                acc0[e] += red[ss][lane][e];
                acc1[e] += red[ss][lane][4 + e];
            }
        const float bv = bias[n];
#pragma unroll
        for (int r = 0; r < 4; ++r) {
            const int t = kg * 4 + r;
            out[t * NDIM + n]        = acc0[r] + bv;
            out[(t + 16) * NDIM + n] = acc1[r] + bv;
        }
    }
}

extern "C" void kernel_launch(void* const* d_in, const int* in_sizes, int n_in,
                              void* d_out, int out_size, void* d_ws, size_t ws_size,
                              hipStream_t stream) {
    const float* x    = (const float*)d_in[0];
    const int*   qw   = (const int*)d_in[1];
    const float* sc   = (const float*)d_in[2];
    const float* zp   = (const float*)d_in[3];
    const float* bias = (const float*)d_in[4];
    float*       out  = (float*)d_out;

    const size_t part_bytes = (size_t)OUTK * PART_ELEMS * sizeof(float); // ~11.3 MB
    const size_t cnt_bytes  = NBC_PAD * sizeof(int);

    if (ws_size >= part_bytes + cnt_bytes) {
        float* part = (float*)d_ws;
        int*   cnt  = (int*)((char*)d_ws + part_bytes);
        hipMemsetAsync(cnt, 0, cnt_bytes, stream);   // reset arrival counters
        awq_gemm2<<<NBC_PAD * OUTK, 512, 0, stream>>>(qw, sc, zp, x, part, cnt,
                                                      bias, out);
    } else {
        awq_gemm_fb<<<NDIM / 16, 256, 0, stream>>>(qw, sc, zp, bias, x, out);
    }
}

// Round 16
// 21.135 us; speedup vs baseline: 1.2878x; 1.2878x over previous
//
#include <hip/hip_runtime.h>
#include <hip/hip_bf16.h>

#define TOKENS 32
#define KDIM   4096
#define NDIM   11008
#define GSZ    64
#define KP     (KDIM/2)          // qweight row length in int32 (2048)
#define NGRP   (KDIM/GSZ)        // 64 groups
#define OUTK   8                 // K-splits across blocks (== 8 XCDs, ob=bi&7)
#define BLK_COLS 128             // 4 waves * 32 cols
#define NBLK_C (NDIM/BLK_COLS)   // 86
#define KSLICE (KDIM/OUTK)       // 512 k per block
#define GPW    (KSLICE/GSZ)      // 8 groups per wave (NO inner kseg split)
#define PART_ELEMS (TOKENS*NDIM) // 352256

typedef float  f32x4 __attribute__((ext_vector_type(4)));
typedef int    i32x4 __attribute__((ext_vector_type(4)));
typedef short  s16x8 __attribute__((ext_vector_type(8)));
typedef _Float16 f16x2 __attribute__((ext_vector_type(2)));
typedef _Float16 f16x8 __attribute__((ext_vector_type(8)));

// Main GEMM: grid = 688 blocks (86 colGroups x 8 outer-ksegs), 256 thr = 4 waves.
// r13 inner loop (f16 packed dequant, swizzled-LDS x) with the inner-kseg
// split REMOVED: each wave owns 16 cols x the full 512-k slice (GPW=8).
// Kills the LDS reduction (2 barriers + 17KB roundtrip + half-idle write) and
// makes the whole grid co-resident (2.7 blocks/CU @ 32KB LDS -> no tail).
// ob = bi&7 -> one outer-kseg per XCD (r15 lesson: per-XCD working set must be
// q 2.8MB + sc/zp 0.7MB + x 64KB < 4MB L2; remapping ob off the XCD axis
// spills sc/zp to L3 and regresses).
// DEQUANT (f16 packed, exact -1024 subtract; r5: no large-const FMA folding):
//   u  = (t&15) | ((t&0xF0)<<12) | 0x64006400   // f16 pair (1024+q), EXACT
//   q2 = pk_add(u, -1024); w = pk_fma(q2, s, -z*s)
__global__ __launch_bounds__(256, 3) void awq_gemm2(
    const int* __restrict__ qw, const float* __restrict__ sc,
    const float* __restrict__ zp, const float* __restrict__ xf,
    float* __restrict__ partial) {
    __shared__ unsigned short xs[TOKENS * KSLICE];   // 32 KB

    const int tid  = threadIdx.x;
    const int lane = tid & 63;
    const int cw   = tid >> 6;       // colWave 0..3
    const int ob   = blockIdx.x & 7;         // outer kseg == XCD
    const int bc   = blockIdx.x >> 3;        // col group 0..85
    const int K0   = ob * KSLICE;

    const int col  = lane & 15;
    const int kg   = lane >> 4;                      // k-subgroup 0..3
    const int n0   = bc * BLK_COLS + cw * 32 + col;  // colset-0 column
    const int sh0  = 8 * (n0 & 3);
    const int* qp0 = qw + (n0 >> 2) * KP + kg * 4;   // colset-1 = +4*KP ints

    struct GD { float s0, z0, s1, z1; i32x4 qa0, qa1, qb0, qb1; };

    auto LOADG = [&](GD& d, int gl) {
        gl = gl < GPW ? gl : GPW - 1;                // clamp prefetch overhang
        const int gg = ob * GPW + gl;                // global group
        d.s0 = sc[gg * NDIM + n0];        d.z0 = zp[gg * NDIM + n0];
        d.s1 = sc[gg * NDIM + n0 + 16];   d.z1 = zp[gg * NDIM + n0 + 16];
        const int* q = qp0 + gg * 32;
        d.qa0 = *reinterpret_cast<const i32x4*>(q);
        d.qa1 = *reinterpret_cast<const i32x4*>(q + 16);
        d.qb0 = *reinterpret_cast<const i32x4*>(q + 4 * KP);
        d.qb1 = *reinterpret_cast<const i32x4*>(q + 4 * KP + 16);
    };

    // ---- q-prefetch for groups 0/1 issued BEFORE staging ----
    GD gA, gB;
    LOADG(gA, 0);
    LOADG(gB, 1);

    // ---- stage x slice: f32 global -> f16 swizzled LDS (32KB, 8 iters) ----
#pragma unroll
    for (int it = 0; it < 8; ++it) {
        const int lin  = it * 4096 + tid * 16;       // byte offset in f16 slice
        const int tok  = lin >> 10;                  // 1024 B per token row
        const int kloc = (lin & 1023) >> 1;
        const float* xp = xf + tok * KDIM + K0 + kloc;
        f32x4 u0 = *reinterpret_cast<const f32x4*>(xp);
        f32x4 u1 = *reinterpret_cast<const f32x4*>(xp + 4);
        s16x8 v;
#pragma unroll
        for (int e = 0; e < 4; ++e) {
            v[e]     = __builtin_bit_cast(short, (_Float16)u0[e]);
            v[e + 4] = __builtin_bit_cast(short, (_Float16)u1[e]);
        }
        *reinterpret_cast<s16x8*>(
            reinterpret_cast<char*>(xs) + (lin ^ ((tok & 7) << 4))) = v;
    }
    __syncthreads();

    f32x4 acc00 = {0,0,0,0}, acc01 = {0,0,0,0};      // [colset][Mtile]
    f32x4 acc10 = {0,0,0,0}, acc11 = {0,0,0,0};

    auto LDSA = [&](int tok, int c) -> f16x8 {       // a-frag from swizzled LDS
        const int inrow = ((c << 6) + (kg << 4)) ^ ((tok & 7) << 4);
        return *reinterpret_cast<const f16x8*>(
            reinterpret_cast<const char*>(xs) + (tok << 10) + inrow);
    };

    const f16x2 m1024 = {(_Float16)(-1024.0f), (_Float16)(-1024.0f)};

    auto DQ = [&](const i32x4& q, f16x2 s2, f16x2 c2) -> f16x8 {
        i32x4 wu;
#pragma unroll
        for (int dd = 0; dd < 4; ++dd) {
            const int t = q[dd] >> sh0;
            const unsigned u = (unsigned)((t & 15) | ((t & 0xF0) << 12)) | 0x64006400u;
            f16x2 qv = __builtin_bit_cast(f16x2, u);
            f16x2 q2 = qv + m1024;                   // exact: q as f16 pair
            f16x2 w  = __builtin_elementwise_fma(q2, s2, c2);
            wu[dd] = __builtin_bit_cast(int, w);
        }
        return __builtin_bit_cast(f16x8, wu);
    };

    auto COMPUTE = [&](const GD& d, int gl) {
        const int c0 = gl * 2;                       // local K32-chunk (0..15)
        f16x8 a00 = LDSA(col, c0),      a01 = LDSA(col + 16, c0);
        f16x8 a10 = LDSA(col, c0 + 1),  a11 = LDSA(col + 16, c0 + 1);
        const _Float16 hs0 = (_Float16)d.s0, hs1 = (_Float16)d.s1;
        const _Float16 hc0 = (_Float16)(-d.z0 * d.s0);
        const _Float16 hc1 = (_Float16)(-d.z1 * d.s1);
        const f16x2 s20 = {hs0, hs0}, c20 = {hc0, hc0};
        const f16x2 s21 = {hs1, hs1}, c21 = {hc1, hc1};
        f16x8 w00 = DQ(d.qa0, s20, c20), w01 = DQ(d.qa1, s20, c20);
        f16x8 w10 = DQ(d.qb0, s21, c21), w11 = DQ(d.qb1, s21, c21);
        acc00 = __builtin_amdgcn_mfma_f32_16x16x32_f16(a00, w00, acc00, 0, 0, 0);
        acc01 = __builtin_amdgcn_mfma_f32_16x16x32_f16(a01, w00, acc01, 0, 0, 0);
        acc10 = __builtin_amdgcn_mfma_f32_16x16x32_f16(a00, w10, acc10, 0, 0, 0);
        acc11 = __builtin_amdgcn_mfma_f32_16x16x32_f16(a01, w10, acc11, 0, 0, 0);
        acc00 = __builtin_amdgcn_mfma_f32_16x16x32_f16(a10, w01, acc00, 0, 0, 0);
        acc01 = __builtin_amdgcn_mfma_f32_16x16x32_f16(a11, w01, acc01, 0, 0, 0);
        acc10 = __builtin_amdgcn_mfma_f32_16x16x32_f16(a10, w11, acc10, 0, 0, 0);
        acc11 = __builtin_amdgcn_mfma_f32_16x16x32_f16(a11, w11, acc11, 0, 0, 0);
    };

#pragma unroll
    for (int gl = 0; gl < GPW; gl += 2) {
        COMPUTE(gA, gl);     LOADG(gA, gl + 2);
        COMPUTE(gB, gl + 1); LOADG(gB, gl + 3);
    }

    // ---- direct partial write (no inner reduction; all waves write) ----
    // D layout (verified m89/m91): col = lane&15, row = (lane>>4)*4 + r
    float* pb = partial + (size_t)ob * PART_ELEMS;
#pragma unroll
    for (int r = 0; r < 4; ++r) {
        const int t = kg * 4 + r;
        pb[t * NDIM + n0]             = acc00[r];
        pb[(t + 16) * NDIM + n0]      = acc01[r];
        pb[t * NDIM + n0 + 16]        = acc10[r];
        pb[(t + 16) * NDIM + n0 + 16] = acc11[r];
    }
}

// Epilogue: out = sum(8 partials) + bias.  88064 f32x4 slots = 688 x 128.
__global__ __launch_bounds__(128) void awq_epi(
    const float* __restrict__ part, const float* __restrict__ bias,
    float* __restrict__ out) {
    const int i = blockIdx.x * 128 + threadIdx.x;    // f32x4 slot, exact fit
    const f32x4* p = reinterpret_cast<const f32x4*>(part);
    f32x4 v = p[i];
#pragma unroll
    for (int o = 1; o < OUTK; ++o) v += p[(size_t)o * (PART_ELEMS / 4) + i];
    v += reinterpret_cast<const f32x4*>(bias)[i % (NDIM / 4)];
    reinterpret_cast<f32x4*>(out)[i] = v;
}

// Fallback (ws too small): round-7 kernel, bf16 path, no ws usage.
__global__ __launch_bounds__(256, 3) void awq_gemm_fb(
    const int* __restrict__ qw, const float* __restrict__ sc,
    const float* __restrict__ zp, const float* __restrict__ bias,
    const float* __restrict__ xf, float* __restrict__ out) {
    const int lane = threadIdx.x & 63;
    const int kseg = threadIdx.x >> 6;
    const int col  = lane & 15;
    const int kg   = lane >> 4;
    const int n    = blockIdx.x * 16 + col;
    const int sh0  = 8 * (n & 3);
    const int* qp  = qw + (n >> 2) * KP + kg * 4;
    const int r0 = col, r1 = col + 16;

    f32x4 acc0 = {0,0,0,0}, acc1 = {0,0,0,0};

    auto cvt8 = [](const float* p) {
        f32x4 u0 = *reinterpret_cast<const f32x4*>(p);
        f32x4 u1 = *reinterpret_cast<const f32x4*>(p + 4);
        s16x8 o;
#pragma unroll
        for (int e = 0; e < 4; ++e) {
            o[e]     = __builtin_bit_cast(short, __float2bfloat16(u0[e]));
            o[e + 4] = __builtin_bit_cast(short, __float2bfloat16(u1[e]));
        }
        return o;
    };

    const int g_lo = kseg * (NGRP / 4), g_hi = g_lo + (NGRP / 4);
#pragma unroll 2
    for (int g = g_lo; g < g_hi; ++g) {
        const float s = sc[g * NDIM + n];
        const float bz = -zp[g * NDIM + n] * s;
#pragma unroll
        for (int h = 0; h < 2; ++h) {
            const int chunk = 2 * g + h;
            i32x4 q = *reinterpret_cast<const i32x4*>(qp + chunk * 16);
            const float* p0 = xf + r0 * KDIM + chunk * 32 + kg * 8;
            const float* p1 = xf + r1 * KDIM + chunk * 32 + kg * 8;
            s16x8 a0 = cvt8(p0), a1 = cvt8(p1);
            s16x8 wf;
#pragma unroll
            for (int dd = 0; dd < 4; ++dd) {
                const int qd = q[dd];
                float w0 = (float)((qd >> sh0) & 15) * s + bz;
                float w1 = (float)((qd >> (sh0 + 4)) & 15) * s + bz;
                wf[2 * dd]     = __builtin_bit_cast(short, __float2bfloat16(w0));
                wf[2 * dd + 1] = __builtin_bit_cast(short, __float2bfloat16(w1));
            }
            acc0 = __builtin_amdgcn_mfma_f32_16x16x32_bf16(a0, wf, acc0, 0, 0, 0);
            acc1 = __builtin_amdgcn_mfma_f32_16x16x32_bf16(a1, wf, acc1, 0, 0, 0);
        }
    }

    __shared__ float red[3][64][9];
    if (kseg != 0) {
#pragma unroll
        for (int e = 0; e < 4; ++e) {
            red[kseg - 1][lane][e]     = acc0[e];
            red[kseg - 1][lane][4 + e] = acc1[e];
        }
    }
    __syncthreads();
    if (kseg == 0) {
#pragma unroll
        for (int ss = 0; ss < 3; ++ss)
#pragma unroll
            for (int e = 0; e < 4; ++e) {
                acc0[e] += red[ss][lane][e];
                acc1[e] += red[ss][lane][4 + e];
            }
        const float bv = bias[n];
#pragma unroll
        for (int r = 0; r < 4; ++r) {
            const int t = kg * 4 + r;
            out[t * NDIM + n]        = acc0[r] + bv;
            out[(t + 16) * NDIM + n] = acc1[r] + bv;
        }
    }
}

extern "C" void kernel_launch(void* const* d_in, const int* in_sizes, int n_in,
                              void* d_out, int out_size, void* d_ws, size_t ws_size,
                              hipStream_t stream) {
    const float* x    = (const float*)d_in[0];
    const int*   qw   = (const int*)d_in[1];
    const float* sc   = (const float*)d_in[2];
    const float* zp   = (const float*)d_in[3];
    const float* bias = (const float*)d_in[4];
    float*       out  = (float*)d_out;

    const size_t part_bytes = (size_t)OUTK * PART_ELEMS * sizeof(float); // ~11.3 MB

    if (ws_size >= part_bytes) {
        float* part = (float*)d_ws;
        awq_gemm2<<<NBLK_C * OUTK, 256, 0, stream>>>(qw, sc, zp, x, part);
        awq_epi<<<PART_ELEMS / 4 / 128, 128, 0, stream>>>(part, bias, out);
    } else {
        awq_gemm_fb<<<NDIM / 16, 256, 0, stream>>>(qw, sc, zp, bias, x, out);
    }
}

// Round 17
// 18.921 us; speedup vs baseline: 1.4385x; 1.1170x over previous
//
#include <hip/hip_runtime.h>
#include <hip/hip_bf16.h>

#define TOKENS 32
#define KDIM   4096
#define NDIM   11008
#define GSZ    64
#define KP     (KDIM/2)          // qweight row length in int32 (2048)
#define NGRP   (KDIM/GSZ)        // 64 groups
#define OUTK   8                 // K-splits across blocks (== 8 XCDs, ob=bi&7)
#define BLK_COLS 128             // 4 colWaves * 32 cols
#define NBLK_C (NDIM/BLK_COLS)   // 86
#define KSLICE (KDIM/OUTK)       // 512 k per block
#define GPW    (KSLICE/2/GSZ)    // 4 groups per wave (2 inner ksegs)
#define PART_ELEMS (TOKENS*NDIM) // 352256

typedef float  f32x4 __attribute__((ext_vector_type(4)));
typedef int    i32x4 __attribute__((ext_vector_type(4)));
typedef short  s16x8 __attribute__((ext_vector_type(8)));
typedef _Float16 f16x2 __attribute__((ext_vector_type(2)));
typedef _Float16 f16x4 __attribute__((ext_vector_type(4)));
typedef _Float16 f16x8 __attribute__((ext_vector_type(8)));

// Main GEMM: grid = 688 blocks, 512 thr = 8 waves.  (r13 structure, 20.2us —
// best; r14 OUTK=4, r15 fused-epi, r16 4-wave all regressed.)
// ob = blockIdx & 7 -> one outer-kseg per XCD: per-XCD set = q 2.8MB +
// sc/zp 0.7MB + x 64KB < 4MB L2 (r15 lesson: keep ob on the XCD axis).
// Wave = (colWave cw 0..3: 32 cols via 2 B-frags) x (inner kseg ks 0..1).
// x staged f32->f16 into XOR-swizzled LDS (byte lin ^ ((tok&7)<<4)).
// DEQUANT (f16 packed, exact -1024 subtract; r5: no large-const FMA folding).
// NEW (r17): partials stored as f16 — halves gemm WRITE (12.4->6.2MB) and epi
// READ (11.3->5.6MB). |partial|<~3, f16 rel 4.9e-4 -> ~5e-3 rms added error,
// zero-mean per element (not a per-group systematic like r5's magic trick).
__global__ __launch_bounds__(512, 2) void awq_gemm2(
    const int* __restrict__ qw, const float* __restrict__ sc,
    const float* __restrict__ zp, const float* __restrict__ xf,
    _Float16* __restrict__ partial) {
    __shared__ unsigned short xs[TOKENS * KSLICE];   // 32 KB (reused for reduce)

    const int tid  = threadIdx.x;
    const int lane = tid & 63;
    const int wid  = tid >> 6;       // 0..7
    const int cw   = wid & 3;        // colWave
    const int ks   = wid >> 2;       // inner kseg 0..1
    const int ob   = blockIdx.x & 7;         // outer kseg == XCD
    const int bc   = blockIdx.x >> 3;        // col group 0..85
    const int K0   = ob * KSLICE;

    const int col  = lane & 15;
    const int kg   = lane >> 4;                      // k-subgroup 0..3
    const int n0   = bc * BLK_COLS + cw * 32 + col;  // colset-0 column
    const int sh0  = 8 * (n0 & 3);
    const int* qp0 = qw + (n0 >> 2) * KP + kg * 4;   // colset-1 = +4*KP ints

    struct GD { float s0, z0, s1, z1; i32x4 qa0, qa1, qb0, qb1; };

    auto LOADG = [&](GD& d, int gl) {
        gl = gl < GPW ? gl : GPW - 1;                // clamp prefetch overhang
        const int gg = ob * (NGRP / OUTK) + ks * GPW + gl;  // global group
        d.s0 = sc[gg * NDIM + n0];        d.z0 = zp[gg * NDIM + n0];
        d.s1 = sc[gg * NDIM + n0 + 16];   d.z1 = zp[gg * NDIM + n0 + 16];
        const int* q = qp0 + gg * 32;
        d.qa0 = *reinterpret_cast<const i32x4*>(q);
        d.qa1 = *reinterpret_cast<const i32x4*>(q + 16);
        d.qb0 = *reinterpret_cast<const i32x4*>(q + 4 * KP);
        d.qb1 = *reinterpret_cast<const i32x4*>(q + 4 * KP + 16);
    };

    // ---- q-prefetch for groups 0/1 issued BEFORE staging ----
    GD gA, gB;
    LOADG(gA, 0);
    LOADG(gB, 1);

    // ---- stage x slice: f32 global -> f16 swizzled LDS (32KB) ----
#pragma unroll
    for (int it = 0; it < 4; ++it) {
        const int lin  = it * 8192 + tid * 16;       // byte offset in f16 slice
        const int tok  = lin >> 10;
        const int kloc = (lin & 1023) >> 1;
        const float* xp = xf + tok * KDIM + K0 + kloc;
        f32x4 u0 = *reinterpret_cast<const f32x4*>(xp);
        f32x4 u1 = *reinterpret_cast<const f32x4*>(xp + 4);
        s16x8 v;
#pragma unroll
        for (int e = 0; e < 4; ++e) {
            v[e]     = __builtin_bit_cast(short, (_Float16)u0[e]);
            v[e + 4] = __builtin_bit_cast(short, (_Float16)u1[e]);
        }
        *reinterpret_cast<s16x8*>(
            reinterpret_cast<char*>(xs) + (lin ^ ((tok & 7) << 4))) = v;
    }
    __syncthreads();

    f32x4 acc00 = {0,0,0,0}, acc01 = {0,0,0,0};      // [colset][Mtile]
    f32x4 acc10 = {0,0,0,0}, acc11 = {0,0,0,0};

    auto LDSA = [&](int tok, int c) -> f16x8 {       // a-frag from swizzled LDS
        const int inrow = ((c << 6) + (kg << 4)) ^ ((tok & 7) << 4);
        return *reinterpret_cast<const f16x8*>(
            reinterpret_cast<const char*>(xs) + (tok << 10) + inrow);
    };

    const f16x2 m1024 = {(_Float16)(-1024.0f), (_Float16)(-1024.0f)};

    auto DQ = [&](const i32x4& q, f16x2 s2, f16x2 c2) -> f16x8 {
        i32x4 wu;
#pragma unroll
        for (int dd = 0; dd < 4; ++dd) {
            const int t = q[dd] >> sh0;
            const unsigned u = (unsigned)((t & 15) | ((t & 0xF0) << 12)) | 0x64006400u;
            f16x2 qv = __builtin_bit_cast(f16x2, u);
            f16x2 q2 = qv + m1024;                   // exact: q as f16 pair
            f16x2 w  = __builtin_elementwise_fma(q2, s2, c2);
            wu[dd] = __builtin_bit_cast(int, w);
        }
        return __builtin_bit_cast(f16x8, wu);
    };

    auto COMPUTE = [&](const GD& d, int gl) {
        const int c0 = ks * 8 + gl * 2;              // local K32-chunk
        f16x8 a00 = LDSA(col, c0),      a01 = LDSA(col + 16, c0);
        f16x8 a10 = LDSA(col, c0 + 1),  a11 = LDSA(col + 16, c0 + 1);
        const _Float16 hs0 = (_Float16)d.s0, hs1 = (_Float16)d.s1;
        const _Float16 hc0 = (_Float16)(-d.z0 * d.s0);
        const _Float16 hc1 = (_Float16)(-d.z1 * d.s1);
        const f16x2 s20 = {hs0, hs0}, c20 = {hc0, hc0};
        const f16x2 s21 = {hs1, hs1}, c21 = {hc1, hc1};
        f16x8 w00 = DQ(d.qa0, s20, c20), w01 = DQ(d.qa1, s20, c20);
        f16x8 w10 = DQ(d.qb0, s21, c21), w11 = DQ(d.qb1, s21, c21);
        acc00 = __builtin_amdgcn_mfma_f32_16x16x32_f16(a00, w00, acc00, 0, 0, 0);
        acc01 = __builtin_amdgcn_mfma_f32_16x16x32_f16(a01, w00, acc01, 0, 0, 0);
        acc10 = __builtin_amdgcn_mfma_f32_16x16x32_f16(a00, w10, acc10, 0, 0, 0);
        acc11 = __builtin_amdgcn_mfma_f32_16x16x32_f16(a01, w10, acc11, 0, 0, 0);
        acc00 = __builtin_amdgcn_mfma_f32_16x16x32_f16(a10, w01, acc00, 0, 0, 0);
        acc01 = __builtin_amdgcn_mfma_f32_16x16x32_f16(a11, w01, acc01, 0, 0, 0);
        acc10 = __builtin_amdgcn_mfma_f32_16x16x32_f16(a10, w11, acc10, 0, 0, 0);
        acc11 = __builtin_amdgcn_mfma_f32_16x16x32_f16(a11, w11, acc11, 0, 0, 0);
    };

#pragma unroll
    for (int gl = 0; gl < GPW; gl += 2) {
        COMPUTE(gA, gl);     LOADG(gA, gl + 2);
        COMPUTE(gB, gl + 1); LOADG(gB, gl + 3);
    }

    // ---- inner-kseg reduction through LDS (reuse xs) ----
    __syncthreads();
    float (*red)[64][17] = reinterpret_cast<float (*)[64][17]>(xs);
    if (ks == 1) {
#pragma unroll
        for (int e = 0; e < 4; ++e) {
            red[cw][lane][e]      = acc00[e];
            red[cw][lane][4 + e]  = acc01[e];
            red[cw][lane][8 + e]  = acc10[e];
            red[cw][lane][12 + e] = acc11[e];
        }
    }
    __syncthreads();
    if (ks == 0) {
#pragma unroll
        for (int e = 0; e < 4; ++e) {
            acc00[e] += red[cw][lane][e];
            acc01[e] += red[cw][lane][4 + e];
            acc10[e] += red[cw][lane][8 + e];
            acc11[e] += red[cw][lane][12 + e];
        }
        // D layout (verified m89/m91): col = lane&15, row = (lane>>4)*4 + r
        _Float16* pb = partial + (size_t)ob * PART_ELEMS;
#pragma unroll
        for (int r = 0; r < 4; ++r) {
            const int t = kg * 4 + r;
            pb[t * NDIM + n0]             = (_Float16)acc00[r];
            pb[(t + 16) * NDIM + n0]      = (_Float16)acc01[r];
            pb[t * NDIM + n0 + 16]        = (_Float16)acc10[r];
            pb[(t + 16) * NDIM + n0 + 16] = (_Float16)acc11[r];
        }
    }
}

// Epilogue: out = sum(8 f16 partials) + bias.  88064 4-col slots = 688 x 128.
__global__ __launch_bounds__(128) void awq_epi(
    const _Float16* __restrict__ part, const float* __restrict__ bias,
    float* __restrict__ out) {
    const int i = blockIdx.x * 128 + threadIdx.x;    // 4-col slot, exact fit
    const f16x4* p = reinterpret_cast<const f16x4*>(part);
    f32x4 v = __builtin_convertvector(p[i], f32x4);
#pragma unroll
    for (int o = 1; o < OUTK; ++o)
        v += __builtin_convertvector(p[(size_t)o * (PART_ELEMS / 4) + i], f32x4);
    v += reinterpret_cast<const f32x4*>(bias)[i % (NDIM / 4)];
    reinterpret_cast<f32x4*>(out)[i] = v;
}

// Fallback (ws too small): round-7 kernel, bf16 path, no ws usage.
__global__ __launch_bounds__(256, 3) void awq_gemm_fb(
    const int* __restrict__ qw, const float* __restrict__ sc,
    const float* __restrict__ zp, const float* __restrict__ bias,
    const float* __restrict__ xf, float* __restrict__ out) {
    const int lane = threadIdx.x & 63;
    const int kseg = threadIdx.x >> 6;
    const int col  = lane & 15;
    const int kg   = lane >> 4;
    const int n    = blockIdx.x * 16 + col;
    const int sh0  = 8 * (n & 3);
    const int* qp  = qw + (n >> 2) * KP + kg * 4;
    const int r0 = col, r1 = col + 16;

    f32x4 acc0 = {0,0,0,0}, acc1 = {0,0,0,0};

    auto cvt8 = [](const float* p) {
        f32x4 u0 = *reinterpret_cast<const f32x4*>(p);
        f32x4 u1 = *reinterpret_cast<const f32x4*>(p + 4);
        s16x8 o;
#pragma unroll
        for (int e = 0; e < 4; ++e) {
            o[e]     = __builtin_bit_cast(short, __float2bfloat16(u0[e]));
            o[e + 4] = __builtin_bit_cast(short, __float2bfloat16(u1[e]));
        }
        return o;
    };

    const int g_lo = kseg * (NGRP / 4), g_hi = g_lo + (NGRP / 4);
#pragma unroll 2
    for (int g = g_lo; g < g_hi; ++g) {
        const float s = sc[g * NDIM + n];
        const float bz = -zp[g * NDIM + n] * s;
#pragma unroll
        for (int h = 0; h < 2; ++h) {
            const int chunk = 2 * g + h;
            i32x4 q = *reinterpret_cast<const i32x4*>(qp + chunk * 16);
            const float* p0 = xf + r0 * KDIM + chunk * 32 + kg * 8;
            const float* p1 = xf + r1 * KDIM + chunk * 32 + kg * 8;
            s16x8 a0 = cvt8(p0), a1 = cvt8(p1);
            s16x8 wf;
#pragma unroll
            for (int dd = 0; dd < 4; ++dd) {
                const int qd = q[dd];
                float w0 = (float)((qd >> sh0) & 15) * s + bz;
                float w1 = (float)((qd >> (sh0 + 4)) & 15) * s + bz;
                wf[2 * dd]     = __builtin_bit_cast(short, __float2bfloat16(w0));
                wf[2 * dd + 1] = __builtin_bit_cast(short, __float2bfloat16(w1));
            }
            acc0 = __builtin_amdgcn_mfma_f32_16x16x32_bf16(a0, wf, acc0, 0, 0, 0);
            acc1 = __builtin_amdgcn_mfma_f32_16x16x32_bf16(a1, wf, acc1, 0, 0, 0);
        }
    }

    __shared__ float red[3][64][9];
    if (kseg != 0) {
#pragma unroll
        for (int e = 0; e < 4; ++e) {
            red[kseg - 1][lane][e]     = acc0[e];
            red[kseg - 1][lane][4 + e] = acc1[e];
        }
    }
    __syncthreads();
    if (kseg == 0) {
#pragma unroll
        for (int ss = 0; ss < 3; ++ss)
#pragma unroll
            for (int e = 0; e < 4; ++e) {
                acc0[e] += red[ss][lane][e];
                acc1[e] += red[ss][lane][4 + e];
            }
        const float bv = bias[n];
#pragma unroll
        for (int r = 0; r < 4; ++r) {
            const int t = kg * 4 + r;
            out[t * NDIM + n]        = acc0[r] + bv;
            out[(t + 16) * NDIM + n] = acc1[r] + bv;
        }
    }
}

extern "C" void kernel_launch(void* const* d_in, const int* in_sizes, int n_in,
                              void* d_out, int out_size, void* d_ws, size_t ws_size,
                              hipStream_t stream) {
    const float* x    = (const float*)d_in[0];
    const int*   qw   = (const int*)d_in[1];
    const float* sc   = (const float*)d_in[2];
    const float* zp   = (const float*)d_in[3];
    const float* bias = (const float*)d_in[4];
    float*       out  = (float*)d_out;

    const size_t part_bytes = (size_t)OUTK * PART_ELEMS * sizeof(_Float16); // ~5.6 MB

    if (ws_size >= part_bytes) {
        _Float16* part = (_Float16*)d_ws;
        awq_gemm2<<<NBLK_C * OUTK, 512, 0, stream>>>(qw, sc, zp, x, part);
        awq_epi<<<PART_ELEMS / 4 / 128, 128, 0, stream>>>(part, bias, out);
    } else {
        awq_gemm_fb<<<NDIM / 16, 256, 0, stream>>>(qw, sc, zp, bias, x, out);
    }
}